// Round 3
// baseline (204.105 us; speedup 1.0000x reference)
//
#include <hip/hip_runtime.h>
#include <math.h>

// GHM-C loss, two-pass, register suffix-accumulators.
//
// MEASURED DEAD ENDS (do not revisit):
//  - R1: LDS ds_add_f32 scatter = ~200 cy effective per atomic (DS pipe wall,
//    VALUBusy only 10%). LDS FP atomics are microcoded-slow on gfx950.
//  - Earlier session: contended global atomics; ballot/s_bcnt counts
//    (VALU->SALU vcc hazard) both regressed.
//  - R2: cutting 9x v_addc via biased sums = NULL (202us unchanged) =>
//    pass1 is NOT issue-bound (issue model ~15us vs ~64us measured, IPC~0.25).
//    It is dependency-STALL-bound: serial exp->log->add front chain + 9x
//    cmp->cndmask->add chains on the same 10 accumulator registers, all 8
//    waves in lockstep.
//
// THIS REVISION (R3): ILP restructure, same math, same biased encoding.
//  - Elements processed in PAIRS with v2f (packed f32) accumulators:
//    A[q] = {sum over even elems, sum over odd elems}. Two independent
//    cmp/cndmask chains per threshold, one v_pk_add_f32 per pair; accumulator
//    chain links ~60 instrs apart -> no stall.
//  - 4 dwordx4 loads issued back-to-back per iteration (16 elems = 8
//    independent pair streams for the scheduler).
//  - Target-row correction applied AFTER per-thread decode, in plain domain
//    (off the hot path).
// Output layout to pass2 unchanged (19 floats: S[0..9], cnt[0..8]).

#define BLK 256
#define GRID 2048
#define BIAS 4096.0f
#define INV_BIAS (1.0f / 4096.0f)

typedef float v4f __attribute__((ext_vector_type(4)));
typedef float v2f __attribute__((ext_vector_type(2)));

// logit(k/10), k=1..9 (exactly antisymmetric in fp32)
__device__ __constant__ float kT[9] = {
    -2.1972246f, -1.3862944f, -0.84729786f, -0.40546511f, 0.0f,
    0.40546511f, 0.84729786f, 1.3862944f, 2.1972246f};

__device__ __forceinline__ void wave_red(float& v) {
#pragma unroll
    for (int off = 32; off > 0; off >>= 1) v += __shfl_down(v, off, 64);
}

// One element pair (xa -> lane .x, xb -> lane .y of each v2f accumulator).
// Biased conditional add: contributes (bce + 4096) so count rides the sum.
__device__ __forceinline__ void upd2(float xa, float xb, v2f& S0, v2f (&A)[9]) {
    float ena = __expf(-fabsf(xa));
    float enb = __expf(-fabsf(xb));
    float la = __logf(1.0f + ena);
    float lb = __logf(1.0f + enb);
    v2f bc;
    bc.x = fmaxf(xa, 0.0f) + la;
    bc.y = fmaxf(xb, 0.0f) + lb;
    S0 += bc;  // v_pk_add_f32
    v2f bb = bc + (v2f)(BIAS);
#pragma unroll
    for (int q = 0; q < 9; ++q) {
        v2f t;
        t.x = (xa >= kT[q]) ? bb.x : 0.0f;  // independent cmp/cndmask chains
        t.y = (xb >= kT[q]) ? bb.y : 0.0f;
        A[q] += t;  // one pk_add per pair per threshold
    }
}

// Single element into the .x half (odd-tail only).
__device__ __forceinline__ void upd1(float x, v2f& S0, v2f (&A)[9]) {
    float en = __expf(-fabsf(x));
    float bce = fmaxf(x, 0.0f) + __logf(1.0f + en);
    S0.x += bce;
    float bb = bce + BIAS;
#pragma unroll
    for (int q = 0; q < 9; ++q) A[q].x += (x >= kT[q]) ? bb : 0.0f;
}

__global__ __launch_bounds__(BLK, 8) void ghmc_pass1(
    const float* __restrict__ pred, const int* __restrict__ target,
    float* __restrict__ blk, unsigned total4, unsigned totalNC, int N, int C) {
    v2f S0 = (v2f)(0.0f);
    v2f A[9];
#pragma unroll
    for (int q = 0; q < 9; ++q) A[q] = (v2f)(0.0f);

    unsigned tid = blockIdx.x * blockDim.x + threadIdx.x;
    unsigned stride = gridDim.x * blockDim.x;
    const v4f* p4 = (const v4f*)pred;

    // 4-wide: four independent dwordx4 loads in flight, 8 pair-streams
    unsigned v = tid;
    for (; v + 3u * stride < total4; v += 4u * stride) {
        v4f a = p4[v];
        v4f b = p4[v + stride];
        v4f c = p4[v + 2u * stride];
        v4f d = p4[v + 3u * stride];
        upd2(a[0], a[1], S0, A);
        upd2(a[2], a[3], S0, A);
        upd2(b[0], b[1], S0, A);
        upd2(b[2], b[3], S0, A);
        upd2(c[0], c[1], S0, A);
        upd2(c[2], c[3], S0, A);
        upd2(d[0], d[1], S0, A);
        upd2(d[2], d[3], S0, A);
    }
    for (; v < total4; v += stride) {
        v4f a = p4[v];
        upd2(a[0], a[1], S0, A);
        upd2(a[2], a[3], S0, A);
    }

    // tail (NC % 4 != 0): global thread 0 only
    if (tid == 0) {
        for (unsigned e = total4 << 2; e < totalNC; ++e) upd1(pred[e], S0, A);
    }

    // Per-thread decode: merge halves, then S'_q = 4096*cnt_q + S_q with
    // |S_q| <= ~420 (<= 65 elems x bce<=6.5) << 2048 -> rint exact.
    float S[10];
    float cnt[9];
    S[0] = S0.x + S0.y;
#pragma unroll
    for (int q = 0; q < 9; ++q) {
        float sp = A[q].x + A[q].y;
        float c = rintf(sp * INV_BIAS);
        cnt[q] = c;
        S[q + 1] = fmaf(c, -BIAS, sp);
    }

    // per-row target correction in PLAIN domain (off the hot path);
    // each row handled exactly once (gridDim.x*BLK = 524288 >= N).
    int row = (int)tid;
    if (row < N) {
        int t = target[row];
        float p = pred[(unsigned)row * (unsigned)C + (unsigned)t];
        float en = __expf(-fabsf(p));
        float l1p = __logf(1.0f + en);
        float bf = fmaxf(p, 0.0f) + l1p;   // streamed s=p contribution (remove)
        float bt = fmaxf(-p, 0.0f) + l1p;  // true s=-p contribution (add)
        S[0] += bt - bf;
#pragma unroll
        for (int q = 0; q < 9; ++q) {
            bool btq = (-p >= kT[q]);
            bool bfq = (p >= kT[q]);
            S[q + 1] += (btq ? bt : 0.0f) - (bfq ? bf : 0.0f);
            cnt[q] += (btq ? 1.0f : 0.0f) - (bfq ? 1.0f : 0.0f);
        }
    }

    // block reduction
#pragma unroll
    for (int i = 0; i < 10; ++i) wave_red(S[i]);
#pragma unroll
    for (int i = 0; i < 9; ++i) wave_red(cnt[i]);

    __shared__ float sS[BLK / 64][10];
    __shared__ float sC[BLK / 64][9];
    int wid = threadIdx.x >> 6;
    int lane = threadIdx.x & 63;
    if (lane == 0) {
#pragma unroll
        for (int i = 0; i < 10; ++i) sS[wid][i] = S[i];
#pragma unroll
        for (int i = 0; i < 9; ++i) sC[wid][i] = cnt[i];
    }
    __syncthreads();
    if (threadIdx.x == 0) {
        const int nw = BLK / 64;
        float o[19];
#pragma unroll
        for (int i = 0; i < 10; ++i) {
            float a = 0.0f;
            for (int w = 0; w < nw; ++w) a += sS[w][i];
            o[i] = a;
        }
#pragma unroll
        for (int i = 0; i < 9; ++i) {
            float a = 0.0f;
            for (int w = 0; w < nw; ++w) a += sC[w][i];
            o[10 + i] = a;  // counts <= 524288, exact in fp32
        }
        float* dst = blk + (unsigned)blockIdx.x * 20u;  // 20-stride: aligned
#pragma unroll
        for (int i = 0; i < 19; ++i) dst[i] = o[i];
    }
}

__global__ __launch_bounds__(256) void ghmc_pass2(
    const float* __restrict__ blk, float* __restrict__ out, int nblocks,
    float totalNC) {
    float P[19];
#pragma unroll
    for (int i = 0; i < 19; ++i) P[i] = 0.0f;

    for (int b = threadIdx.x; b < nblocks; b += 256) {
        const float* src = blk + (unsigned)b * 20u;
#pragma unroll
        for (int i = 0; i < 19; ++i) P[i] += src[i];
    }
#pragma unroll
    for (int i = 0; i < 19; ++i) wave_red(P[i]);

    __shared__ float sP[4][19];
    int wid = threadIdx.x >> 6;
    int lane = threadIdx.x & 63;
    if (lane == 0) {
#pragma unroll
        for (int i = 0; i < 19; ++i) sP[wid][i] = P[i];
    }
    __syncthreads();
    if (threadIdx.x == 0) {
        float Sv[11], Cv[11];
        for (int i = 0; i < 19; ++i) {
            float a = 0.0f;
            for (int w = 0; w < 4; ++w) a += sP[w][i];
            P[i] = a;
        }
        for (int i = 0; i < 10; ++i) Sv[i] = P[i];
        Sv[10] = 0.0f;
        Cv[0] = totalNC;
        for (int i = 1; i < 10; ++i) Cv[i] = P[9 + i];
        Cv[10] = 0.0f;

        int nonempty = 0;
        for (int b = 0; b < 10; ++b)
            if (Cv[b] - Cv[b + 1] > 0.5f) nonempty++;
        float n = fmaxf((float)nonempty, 1.0f);

        float loss = 0.0f;
        for (int b = 0; b < 10; ++b) {
            float c = Cv[b] - Cv[b + 1];
            if (c > 0.5f) loss += (Sv[b] - Sv[b + 1]) / (c * n);
        }
        out[0] = loss;  // LOSS_WEIGHT = 1.0
    }
}

extern "C" void kernel_launch(void* const* d_in, const int* in_sizes, int n_in,
                              void* d_out, int out_size, void* d_ws, size_t ws_size,
                              hipStream_t stream) {
    const float* pred = (const float*)d_in[0];
    const int* target = (const int*)d_in[1];
    int NC = in_sizes[0];
    int N = in_sizes[1];
    int C = NC / N;
    unsigned total4 = (unsigned)(NC / 4);

    int blocks = GRID;
    size_t per_block = 20 * sizeof(float);
    if (ws_size < (size_t)blocks * per_block) {
        size_t maxb = ws_size / per_block;
        blocks = (int)(maxb > 0 ? maxb : 1);
    }
    // per-row correction requires blocks*BLK >= N (2048*256 = 524288 >= 32768)

    float* blkbuf = (float*)d_ws;

    ghmc_pass1<<<blocks, BLK, 0, stream>>>(pred, target, blkbuf, total4,
                                           (unsigned)NC, N, C);
    ghmc_pass2<<<1, 256, 0, stream>>>(blkbuf, (float*)d_out, blocks, (float)NC);
}